// Round 1
// 182.159 us; speedup vs baseline: 1.0003x; 1.0003x over previous
//
#include <hip/hip_runtime.h>
#include <hip/hip_bf16.h>

// Problem constants
#define QSTRIDE 147584   // per-sample question_rep stride (128*128*9 + 128)
#define WOFF    147456   // bias offset within question_rep row

typedef __attribute__((ext_vector_type(8))) short bf16x8;
typedef __attribute__((ext_vector_type(4))) float f32x4;

static __device__ __forceinline__ ushort f2bf(float f) {
  union { float f; unsigned u; } x; x.f = f;
  unsigned r = x.u + 0x7fffu + ((x.u >> 16) & 1u);  // RNE bf16 (finite inputs)
  return (ushort)(r >> 16);
}
static __device__ __forceinline__ unsigned pk2(ushort a, ushort b) {
  return (unsigned)a | ((unsigned)b << 16);
}
// async global->LDS DMA: 16B per active lane, lands at ldsbase + lane*16
static __device__ __forceinline__ void async16(const ushort* g, ushort* l) {
  __builtin_amdgcn_global_load_lds((const __attribute__((address_space(1))) void*)g,
                                   (__attribute__((address_space(3))) void*)l, 16, 0, 0);
}

// ---------------------------------------------------------------------------
// 1) question_rep weights -> wt2[b][tap][cq][o][ci32] bf16
//    LDS-staged: coalesced 256B/wave global reads, per-thread pick from LDS.
//    block = (b, ogrp of 16 o's); 4 rounds of 4 o's each.
// ---------------------------------------------------------------------------
__global__ __launch_bounds__(256) void pack_w_kernel(const float* __restrict__ q,
                                                     ushort* __restrict__ wt2) {
  __shared__ float Ls[4608];                 // 4 o's x 1152 floats
  int b = blockIdx.x >> 3, ogrp = blockIdx.x & 7;
  int t = threadIdx.x;
  const float* gbase = q + (size_t)b * QSTRIDE + (size_t)ogrp * 16 * 1152;
  ushort* dstb = wt2 + (size_t)b * 147456;
  int o_loc = t >> 6;                        // wave id = local o
  int ci    = (t & 63) * 2;                  // 2 channels per thread
  int cq    = ci >> 5, coff = ci & 31;
  for (int r = 0; r < 4; ++r) {
    __syncthreads();                         // previous round's LDS reads done
    const float* gs = gbase + r * 4608;
#pragma unroll
    for (int i = 0; i < 18; ++i) Ls[i * 256 + t] = gs[i * 256 + t];
    __syncthreads();
    int o_full = ogrp * 16 + r * 4 + o_loc;
    const float* v = Ls + o_loc * 1152 + ci * 9;   // 18 consecutive floats
    float a[18];
#pragma unroll
    for (int i = 0; i < 18; ++i) a[i] = v[i];
    ushort* dd = dstb + (size_t)cq * 4096 + o_full * 32 + coff;
#pragma unroll
    for (int tap = 0; tap < 9; ++tap) {
      unsigned pkv = pk2(f2bf(a[tap]), f2bf(a[9 + tap]));  // {ci, ci+1}
      *(unsigned*)(dd + (size_t)tap * 16384) = pkv;
    }
  }
}

// ---------------------------------------------------------------------------
// 2) proj_w (128x256 fp32) -> pwb2[cq][o][c32] bf16 (chunk-major, DMA-able)
// ---------------------------------------------------------------------------
__global__ __launch_bounds__(256) void pack_pw_kernel(const float* __restrict__ pw,
                                                      ushort* __restrict__ pwb2) {
  int tg = blockIdx.x * 256 + threadIdx.x;   // 4096 threads
  int o  = tg >> 5;
  int c0 = (tg & 31) * 8;
  const float4* s4 = (const float4*)(pw + (size_t)o * 256 + c0);
  float4 f0 = s4[0], f1 = s4[1];
  uint4 pkv;
  pkv.x = pk2(f2bf(f0.x), f2bf(f0.y)); pkv.y = pk2(f2bf(f0.z), f2bf(f0.w));
  pkv.z = pk2(f2bf(f1.x), f2bf(f1.y)); pkv.w = pk2(f2bf(f1.z), f2bf(f1.w));
  *(uint4*)(pwb2 + (size_t)(c0 >> 5) * 4096 + o * 32 + (c0 & 31)) = pkv;
}

// ---------------------------------------------------------------------------
// 3) zero the halo of xp2[b][cq][34][34][32]
// ---------------------------------------------------------------------------
__global__ __launch_bounds__(256) void zero_border_kernel(ushort* __restrict__ xp2) {
  int b = blockIdx.x, t = threadIdx.x;
  for (int idx = t; idx < 528; idx += 256) {
    int cq = idx / 132, r = idx - cq * 132;
    int hp, wp;
    if (r < 34)       { hp = 0;        wp = r; }
    else if (r < 68)  { hp = 33;       wp = r - 34; }
    else if (r < 100) { hp = r - 67;   wp = 0; }     // 1..32
    else              { hp = r - 99;   wp = 33; }    // 1..32
    uint4 z = {0u,0u,0u,0u};
    uint4* dst = (uint4*)(xp2 + (((size_t)b * 4 + cq) * 1156 + hp * 34 + wp) * 32);
#pragma unroll
    for (int i = 0; i < 4; ++i) dst[i] = z;
  }
}

// ---------------------------------------------------------------------------
// 4) Fused projection: reads lhs/rhs NCHW fp32 directly, register-transposes
//    into B-tiles, MFMA GEMM (M=128 o, N=128 px, K=256), writes xp2 bf16 NHWC.
//    Software-pipelined: chunk c+1's register loads + As DMA are issued AFTER
//    barrier B of chunk c, so their ~900cy HBM latency hides under the MFMA
//    phase. Barrier A is a raw lgkmcnt-only barrier (no vmcnt(0) drain) so
//    in-flight prefetches survive it. As is double-buffered.
// ---------------------------------------------------------------------------
__global__ __launch_bounds__(256, 2) void proj_kernel(const ushort* __restrict__ pwb2,
                                                      const float* __restrict__ lhs,
                                                      const float* __restrict__ rhs,
                                                      const float* __restrict__ pb,
                                                      ushort* __restrict__ xp2) {
  __shared__ ushort As[2][4096];             // double-buffered A (8 KB each)
  __shared__ ushort Bs[4096];
  int b = blockIdx.y, tile = blockIdx.x;
  int p0 = tile * 128;
  int t = threadIdx.x;
  int lane = t & 63, wv = t >> 6;
  int m0 = (wv & 1) * 64, n0 = (wv >> 1) * 64;
  int quad = lane >> 4, li = lane & 15;
  f32x4 acc[4][4] = {};
  int cgrp = t & 3;                 // 8-channel group within 32-chunk
  int pq   = t >> 2;                // 0..63 -> pixel pair 2pq, 2pq+1

  const float* base_l = lhs + (size_t)b * 131072 + (size_t)(cgrp * 8) * 1024 + p0 + 2 * pq;
  const float* base_r = rhs + (size_t)b * 131072 + (size_t)(cgrp * 8) * 1024 + p0 + 2 * pq;

#define PROJ_DMA(c, buf) do { \
    const ushort* ag_ = pwb2 + (size_t)(c) * 4096; \
    async16(ag_ + (size_t)wv * 512 + lane * 8,       As[buf] + wv * 512); \
    async16(ag_ + (size_t)(wv + 4) * 512 + lane * 8, As[buf] + (wv + 4) * 512); \
  } while (0)

#define PROJ_LOAD(c, fb) do { \
    const float* src_ = ((c) < 4 ? base_l : base_r) + (size_t)(((c) & 3) * 32) * 1024; \
    _Pragma("unroll") \
    for (int j = 0; j < 8; ++j) fb[j] = *(const float2*)(src_ + (size_t)j * 1024); \
  } while (0)

#define PROJ_PACK(fb) do { \
    pk0.x = pk2(f2bf(fb[0].x), f2bf(fb[1].x)); \
    pk0.y = pk2(f2bf(fb[2].x), f2bf(fb[3].x)); \
    pk0.z = pk2(f2bf(fb[4].x), f2bf(fb[5].x)); \
    pk0.w = pk2(f2bf(fb[6].x), f2bf(fb[7].x)); \
    pk1.x = pk2(f2bf(fb[0].y), f2bf(fb[1].y)); \
    pk1.y = pk2(f2bf(fb[2].y), f2bf(fb[3].y)); \
    pk1.z = pk2(f2bf(fb[4].y), f2bf(fb[5].y)); \
    pk1.w = pk2(f2bf(fb[6].y), f2bf(fb[7].y)); \
  } while (0)

  float2 fb0[8], fb1[8];
  PROJ_DMA(0, 0);                            // prologue: chunk 0 in flight
  PROJ_LOAD(0, fb0);

#pragma unroll
  for (int c = 0; c < 8; ++c) {
    uint4 pk0, pk1;
    if (c & 1) PROJ_PACK(fb1); else PROJ_PACK(fb0);   // waits chunk c loads (drains DMA c too)
    // barrier A: write-after-read protection for Bs / As[(c+1)&1].
    // lgkmcnt(0) only -- no vmcnt drain, prefetches stay in flight.
    asm volatile("s_waitcnt lgkmcnt(0)" ::: "memory");
    __builtin_amdgcn_s_barrier();
    *(uint4*)(Bs + (size_t)(2*pq)   * 32 + cgrp * 8) = pk0;
    *(uint4*)(Bs + (size_t)(2*pq+1) * 32 + cgrp * 8) = pk1;
    __syncthreads();   // barrier B: ds_writes + DMA visible (vmcnt already 0 here)
    if (c < 7) {       // prefetch chunk c+1 -- latency hides under MFMA below
      PROJ_DMA(c + 1, (c + 1) & 1);
      if (c & 1) PROJ_LOAD(c + 1, fb0); else PROJ_LOAD(c + 1, fb1);
    }
    const ushort* ar = As[c & 1];
    bf16x8 af[4], bg[4];
#pragma unroll
    for (int mi = 0; mi < 4; ++mi)
      af[mi] = *(const bf16x8*)(ar + (m0 + mi*16 + li) * 32 + quad * 8);
#pragma unroll
    for (int ni = 0; ni < 4; ++ni)
      bg[ni] = *(const bf16x8*)(Bs + (n0 + ni*16 + li) * 32 + quad * 8);
#pragma unroll
    for (int mi = 0; mi < 4; ++mi)
#pragma unroll
      for (int ni = 0; ni < 4; ++ni)
        acc[mi][ni] = __builtin_amdgcn_mfma_f32_16x16x32_bf16(af[mi], bg[ni], acc[mi][ni], 0, 0, 0);
  }

  ushort* xpb = xp2 + (size_t)b * 4 * 1156 * 32;
#pragma unroll
  for (int mi = 0; mi < 4; ++mi) {
    int o0 = m0 + mi*16 + quad*4;
    float4 bias = *(const float4*)(pb + o0);
#pragma unroll
    for (int ni = 0; ni < 4; ++ni) {
      int p = p0 + n0 + ni*16 + li;
      int h = p >> 5, w = p & 31;
      ushort* dp = xpb + ((size_t)(o0 >> 5) * 1156 + (h + 1) * 34 + (w + 1)) * 32 + (o0 & 31);
      f32x4 a = acc[mi][ni];
      uint2 pkv;
      pkv.x = pk2(f2bf(a.x + bias.x), f2bf(a.y + bias.y));
      pkv.y = pk2(f2bf(a.z + bias.z), f2bf(a.w + bias.w));
      *(uint2*)dp = pkv;
    }
  }
#undef PROJ_DMA
#undef PROJ_LOAD
#undef PROJ_PACK
}

// ---------------------------------------------------------------------------
// 5) Conv implicit GEMM, cq-outer / tap-inner:
//    - B super-tile (6 rows x 34 px, 13KB) staged ONCE per cq, reused by 9 taps
//    - A (8KB per tap) double-buffered, prefetched right after the barrier
//    - b = blk&63: the 8 tile-blocks of a sample share one XCD's L2 for wt2
// ---------------------------------------------------------------------------
__global__ __launch_bounds__(256, 2) void conv_kernel(const ushort* __restrict__ wt2,
                                                      const ushort* __restrict__ xp2,
                                                      const float* __restrict__ q,
                                                      float* __restrict__ out) {
  __shared__ ushort As[2][4096];
  __shared__ ushort Bs[6528];                // 6*34*32
  int blk = blockIdx.x;
  int b = blk & 63, tile = blk >> 6;
  int p0 = tile * 128, h0 = tile * 4;
  int t = threadIdx.x;
  int lane = t & 63, wv = t >> 6;
  int m0 = (wv & 1) * 64, n0 = (wv >> 1) * 64;
  int quad = lane >> 4, li = lane & 15;
  f32x4 acc[4][4] = {};
  const ushort* wtb = wt2 + (size_t)b * 147456;
  const ushort* xpb = xp2 + (size_t)b * 147968;   // 4*1156*32

  for (int cq = 0; cq < 4; ++cq) {
    __syncthreads();                         // prior compute's LDS reads done
    // stage B super-tile: one linear 13,056B copy (816 x 16B)
    {
      const ushort* bgp = xpb + (size_t)(cq * 1156 + h0 * 34) * 32;
#pragma unroll
      for (int p = 0; p < 3; ++p)
        async16(bgp + (size_t)(p * 256 + t) * 8, Bs + p * 2048 + wv * 512);
      if (t < 48)                            // wv==0: tail 48 lanes
        async16(bgp + (size_t)(768 + t) * 8, Bs + 6144);
    }
    // stage A(cq, tap=0) -> As[0]
    {
      const ushort* ag = wtb + (size_t)cq * 4096;
      async16(ag + (size_t)t * 8,         As[0] + wv * 512);
      async16(ag + (size_t)(256 + t) * 8, As[0] + 2048 + wv * 512);
    }
    for (int tap = 0; tap < 9; ++tap) {
      __syncthreads();                       // vmcnt(0) drain: staged data visible
      if (tap < 8) {                         // prefetch next tap's A (overlaps MFMA)
        const ushort* ag = wtb + (size_t)((tap + 1) * 4 + cq) * 4096;
        ushort* ab = As[(tap + 1) & 1];
        async16(ag + (size_t)t * 8,         ab + wv * 512);
        async16(ag + (size_t)(256 + t) * 8, ab + 2048 + wv * 512);
      }
      int kh = tap / 3, kw = tap - kh * 3;
      const ushort* ar = As[tap & 1];
      bf16x8 af[4], bg[4];
#pragma unroll
      for (int mi = 0; mi < 4; ++mi)
        af[mi] = *(const bf16x8*)(ar + (m0 + mi*16 + li) * 32 + quad * 8);
#pragma unroll
      for (int ni = 0; ni < 4; ++ni) {
        int pl = n0 + ni*16 + li;
        int h = pl >> 5, w = pl & 31;
        bg[ni] = *(const bf16x8*)(Bs + ((h + kh) * 34 + (w + kw)) * 32 + quad * 8);
      }
#pragma unroll
      for (int mi = 0; mi < 4; ++mi)
#pragma unroll
        for (int ni = 0; ni < 4; ++ni)
          acc[mi][ni] = __builtin_amdgcn_mfma_f32_16x16x32_bf16(af[mi], bg[ni], acc[mi][ni], 0, 0, 0);
    }
  }

  const float* qb = q + (size_t)b * QSTRIDE + WOFF;
  float* ob = out + (size_t)b * 128 * 1024 + p0;
#pragma unroll
  for (int mi = 0; mi < 4; ++mi) {
    int o0 = m0 + mi*16 + quad*4;
    float4 bias = *(const float4*)(qb + o0);
#pragma unroll
    for (int ni = 0; ni < 4; ++ni) {
      int pl = n0 + ni*16 + li;
      float* dp = ob + (size_t)o0 * 1024 + pl;
      f32x4 a = acc[mi][ni];
      dp[0]    = a.x + bias.x;
      dp[1024] = a.y + bias.y;
      dp[2048] = a.z + bias.z;
      dp[3072] = a.w + bias.w;
    }
  }
}

extern "C" void kernel_launch(void* const* d_in, const int* in_sizes, int n_in,
                              void* d_out, int out_size, void* d_ws, size_t ws_size,
                              hipStream_t stream) {
  const float* q   = (const float*)d_in[0];
  const float* lhs = (const float*)d_in[1];
  const float* rhs = (const float*)d_in[2];
  const float* pw  = (const float*)d_in[3];
  const float* pb  = (const float*)d_in[4];
  float* out = (float*)d_out;

  // workspace layout (37,879,808 B total)
  char* ws = (char*)d_ws;
  ushort* wt2  = (ushort*)(ws);               // 18,874,368 B : wt2[b][tap][cq][o][32]
  ushort* pwb2 = (ushort*)(ws + 18874368);    //     65,536 B : pwb2[cq][o][32]
  ushort* xp2  = (ushort*)(ws + 18939904);    // 18,939,904 B : xp2[b][cq][34][34][32]

  pack_w_kernel     <<<512, 256, 0, stream>>>(q, wt2);
  pack_pw_kernel    <<<16,  256, 0, stream>>>(pw, pwb2);
  zero_border_kernel<<<64,  256, 0, stream>>>(xp2);
  proj_kernel       <<<dim3(8, 64), 256, 0, stream>>>(pwb2, lhs, rhs, pb, xp2);
  conv_kernel       <<<512, 256, 0, stream>>>(wt2, xp2, q, out);
}

// Round 3
// 177.684 us; speedup vs baseline: 1.0255x; 1.0252x over previous
//
#include <hip/hip_runtime.h>
#include <hip/hip_bf16.h>

// Problem constants
#define QSTRIDE 147584   // per-sample question_rep stride (128*128*9 + 128)
#define WOFF    147456   // bias offset within question_rep row

typedef __attribute__((ext_vector_type(8))) short bf16x8;
typedef __attribute__((ext_vector_type(4))) float f32x4;

static __device__ __forceinline__ ushort f2bf(float f) {
  union { float f; unsigned u; } x; x.f = f;
  unsigned r = x.u + 0x7fffu + ((x.u >> 16) & 1u);  // RNE bf16 (finite inputs)
  return (ushort)(r >> 16);
}
static __device__ __forceinline__ unsigned pk2(ushort a, ushort b) {
  return (unsigned)a | ((unsigned)b << 16);
}
// async global->LDS DMA: 16B per active lane, lands at ldsbase + lane*16
static __device__ __forceinline__ void async16(const ushort* g, ushort* l) {
  __builtin_amdgcn_global_load_lds((const __attribute__((address_space(1))) void*)g,
                                   (__attribute__((address_space(3))) void*)l, 16, 0, 0);
}

// Barrier with counted vmcnt + full LDS drain.
// lgkmcnt(0) is REQUIRED: without it a wave can cross the barrier with its
// ds_reads of the previous step still outstanding, racing the next step's
// global_load_lds overwrite of the same LDS buffer (round-2 failure).
// vmcnt stays counted so prefetches survive the barrier.
#define WAITBAR_(vm) asm volatile("s_waitcnt vmcnt(" #vm ") lgkmcnt(0)\n\ts_barrier" ::: "memory")
#define WAITBAR(vm) WAITBAR_(vm)
// raw barrier draining only LDS ops (ds ops visible), vm queue untouched
#define BARSYNC() asm volatile("s_waitcnt lgkmcnt(0)\n\ts_barrier" ::: "memory")

// ---------------------------------------------------------------------------
// 1) question_rep weights -> wt2[b][tap][cq][o][ci32] bf16
// ---------------------------------------------------------------------------
__global__ __launch_bounds__(256) void pack_w_kernel(const float* __restrict__ q,
                                                     ushort* __restrict__ wt2) {
  __shared__ float Ls[4608];                 // 4 o's x 1152 floats
  int b = blockIdx.x >> 3, ogrp = blockIdx.x & 7;
  int t = threadIdx.x;
  const float* gbase = q + (size_t)b * QSTRIDE + (size_t)ogrp * 16 * 1152;
  ushort* dstb = wt2 + (size_t)b * 147456;
  int o_loc = t >> 6;                        // wave id = local o
  int ci    = (t & 63) * 2;                  // 2 channels per thread
  int cq    = ci >> 5, coff = ci & 31;
  for (int r = 0; r < 4; ++r) {
    __syncthreads();                         // previous round's LDS reads done
    const float* gs = gbase + r * 4608;
#pragma unroll
    for (int i = 0; i < 18; ++i) Ls[i * 256 + t] = gs[i * 256 + t];
    __syncthreads();
    int o_full = ogrp * 16 + r * 4 + o_loc;
    const float* v = Ls + o_loc * 1152 + ci * 9;   // 18 consecutive floats
    float a[18];
#pragma unroll
    for (int i = 0; i < 18; ++i) a[i] = v[i];
    ushort* dd = dstb + (size_t)cq * 4096 + o_full * 32 + coff;
#pragma unroll
    for (int tap = 0; tap < 9; ++tap) {
      unsigned pkv = pk2(f2bf(a[tap]), f2bf(a[9 + tap]));  // {ci, ci+1}
      *(unsigned*)(dd + (size_t)tap * 16384) = pkv;
    }
  }
}

// ---------------------------------------------------------------------------
// 2) proj_w (128x256 fp32) -> pwb2[cq][o][c32] bf16 (chunk-major, DMA-able)
// ---------------------------------------------------------------------------
__global__ __launch_bounds__(256) void pack_pw_kernel(const float* __restrict__ pw,
                                                      ushort* __restrict__ pwb2) {
  int tg = blockIdx.x * 256 + threadIdx.x;   // 4096 threads
  int o  = tg >> 5;
  int c0 = (tg & 31) * 8;
  const float4* s4 = (const float4*)(pw + (size_t)o * 256 + c0);
  float4 f0 = s4[0], f1 = s4[1];
  uint4 pkv;
  pkv.x = pk2(f2bf(f0.x), f2bf(f0.y)); pkv.y = pk2(f2bf(f0.z), f2bf(f0.w));
  pkv.z = pk2(f2bf(f1.x), f2bf(f1.y)); pkv.w = pk2(f2bf(f1.z), f2bf(f1.w));
  *(uint4*)(pwb2 + (size_t)(c0 >> 5) * 4096 + o * 32 + (c0 & 31)) = pkv;
}

// ---------------------------------------------------------------------------
// 3) zero the halo of xp2[b][cq][34][34][32]
// ---------------------------------------------------------------------------
__global__ __launch_bounds__(256) void zero_border_kernel(ushort* __restrict__ xp2) {
  int b = blockIdx.x, t = threadIdx.x;
  for (int idx = t; idx < 528; idx += 256) {
    int cq = idx / 132, r = idx - cq * 132;
    int hp, wp;
    if (r < 34)       { hp = 0;        wp = r; }
    else if (r < 68)  { hp = 33;       wp = r - 34; }
    else if (r < 100) { hp = r - 67;   wp = 0; }     // 1..32
    else              { hp = r - 99;   wp = 33; }    // 1..32
    uint4 z = {0u,0u,0u,0u};
    uint4* dst = (uint4*)(xp2 + (((size_t)b * 4 + cq) * 1156 + hp * 34 + wp) * 32);
#pragma unroll
    for (int i = 0; i < 4; ++i) dst[i] = z;
  }
}

// ---------------------------------------------------------------------------
// 4) Fused projection, depth-2 software pipeline:
//    - fb[3] register buffers + As[3] LDS ring: chunk c+2 issued at iter c,
//      waited at iter c+2 -> ~2 compute phases (~800cy) of latency cover.
//    - Bs double-buffered -> single raw barrier per iteration (lgkmcnt only,
//      vm queue never drained by a barrier; DMA(c) retirement is forced by
//      the pack's compiler-inserted vmcnt wait on LOAD(c), which is newer).
//    - sched_barrier(0) pins prefetch issues above the MFMA cluster.
// ---------------------------------------------------------------------------
__global__ __launch_bounds__(256, 2) void proj_kernel(const ushort* __restrict__ pwb2,
                                                      const float* __restrict__ lhs,
                                                      const float* __restrict__ rhs,
                                                      const float* __restrict__ pb,
                                                      ushort* __restrict__ xp2) {
  __shared__ ushort As[3][4096];             // A ring (8 KB each)
  __shared__ ushort Bs[2][4096];             // B double buffer
  int b = blockIdx.y, tile = blockIdx.x;
  int p0 = tile * 128;
  int t = threadIdx.x;
  int lane = t & 63, wv = t >> 6;
  int m0 = (wv & 1) * 64, n0 = (wv >> 1) * 64;
  int quad = lane >> 4, li = lane & 15;
  f32x4 acc[4][4] = {};
  int cgrp = t & 3;                 // 8-channel group within 32-chunk
  int pq   = t >> 2;                // 0..63 -> pixel pair 2pq, 2pq+1

  const float* base_l = lhs + (size_t)b * 131072 + (size_t)(cgrp * 8) * 1024 + p0 + 2 * pq;
  const float* base_r = rhs + (size_t)b * 131072 + (size_t)(cgrp * 8) * 1024 + p0 + 2 * pq;

  float2 fb[3][8];

#define PROJ_DMA(c, buf) do { \
    const ushort* ag_ = pwb2 + (size_t)(c) * 4096; \
    async16(ag_ + (size_t)wv * 512 + lane * 8,       &As[buf][0] + wv * 512); \
    async16(ag_ + (size_t)(wv + 4) * 512 + lane * 8, &As[buf][0] + (wv + 4) * 512); \
  } while (0)

#define PROJ_LOAD(c, sl) do { \
    const float* src_ = ((c) < 4 ? base_l : base_r) + (size_t)(((c) & 3) * 32) * 1024; \
    _Pragma("unroll") \
    for (int j = 0; j < 8; ++j) fb[sl][j] = *(const float2*)(src_ + (size_t)j * 1024); \
  } while (0)

  // prologue: chunks 0 and 1 in flight
  PROJ_DMA(0, 0); PROJ_LOAD(0, 0);
  PROJ_DMA(1, 1); PROJ_LOAD(1, 1);

#pragma unroll
  for (int c = 0; c < 8; ++c) {
    const int sl = c % 3;
    uint4 pk0, pk1;
    // pack waits (counted vmcnt, compiler-inserted) on fb[sl] issued 2 iters ago
    pk0.x = pk2(f2bf(fb[sl][0].x), f2bf(fb[sl][1].x));
    pk0.y = pk2(f2bf(fb[sl][2].x), f2bf(fb[sl][3].x));
    pk0.z = pk2(f2bf(fb[sl][4].x), f2bf(fb[sl][5].x));
    pk0.w = pk2(f2bf(fb[sl][6].x), f2bf(fb[sl][7].x));
    pk1.x = pk2(f2bf(fb[sl][0].y), f2bf(fb[sl][1].y));
    pk1.y = pk2(f2bf(fb[sl][2].y), f2bf(fb[sl][3].y));
    pk1.z = pk2(f2bf(fb[sl][4].y), f2bf(fb[sl][5].y));
    pk1.w = pk2(f2bf(fb[sl][6].y), f2bf(fb[sl][7].y));
    {
      ushort* bw = &Bs[c & 1][0];
      *(uint4*)(bw + (size_t)(2*pq)   * 32 + cgrp * 8) = pk0;
      *(uint4*)(bw + (size_t)(2*pq+1) * 32 + cgrp * 8) = pk1;
    }
    BARSYNC();               // ds_writes drained + this iter's DMA (landed at pack) visible
    if (c < 6) {             // prefetch chunk c+2 -- 2 compute phases of cover
      PROJ_DMA(c + 2, (c + 2) % 3);
      PROJ_LOAD(c + 2, (c + 2) % 3);
    }
    __builtin_amdgcn_sched_barrier(0);   // pin issues above the MFMA cluster
    const ushort* ar = &As[c % 3][0];
    const ushort* br = &Bs[c & 1][0];
    bf16x8 af[4], bg[4];
#pragma unroll
    for (int mi = 0; mi < 4; ++mi)
      af[mi] = *(const bf16x8*)(ar + (m0 + mi*16 + li) * 32 + quad * 8);
#pragma unroll
    for (int ni = 0; ni < 4; ++ni)
      bg[ni] = *(const bf16x8*)(br + (n0 + ni*16 + li) * 32 + quad * 8);
#pragma unroll
    for (int mi = 0; mi < 4; ++mi)
#pragma unroll
      for (int ni = 0; ni < 4; ++ni)
        acc[mi][ni] = __builtin_amdgcn_mfma_f32_16x16x32_bf16(af[mi], bg[ni], acc[mi][ni], 0, 0, 0);
  }
#undef PROJ_DMA
#undef PROJ_LOAD

  ushort* xpb = xp2 + (size_t)b * 4 * 1156 * 32;
#pragma unroll
  for (int mi = 0; mi < 4; ++mi) {
    int o0 = m0 + mi*16 + quad*4;
    float4 bias = *(const float4*)(pb + o0);
#pragma unroll
    for (int ni = 0; ni < 4; ++ni) {
      int p = p0 + n0 + ni*16 + li;
      int h = p >> 5, w = p & 31;
      ushort* dp = xpb + ((size_t)(o0 >> 5) * 1156 + (h + 1) * 34 + (w + 1)) * 32 + (o0 & 31);
      f32x4 a = acc[mi][ni];
      uint2 pkv;
      pkv.x = pk2(f2bf(a.x + bias.x), f2bf(a.y + bias.y));
      pkv.y = pk2(f2bf(a.z + bias.z), f2bf(a.w + bias.w));
      *(uint2*)dp = pkv;
    }
  }
}

// ---------------------------------------------------------------------------
// 5) Conv implicit GEMM, 36 flattened (cq,tap) steps with COUNTED vmcnt:
//    - As[3] ring, depth-2 prefetch (A(s+2) issued at step s); buf = tap%3
//    - Bs[2], next cq's 13KB super-tile issued at tap 6 (3 steps of cover,
//      in-order forced-drain lands exactly at tap 0 where it's needed)
//    - one raw barrier per step: counted vmcnt + lgkmcnt(0) (the lgkmcnt
//      drain closes the cross-wave WAR race on the As ring / Bs buffers)
//    - B staging uniform per wave (4 DMA instrs: 204 lines, masked tail)
//      so per-wave vmcnt counts are exact
// ---------------------------------------------------------------------------
__global__ __launch_bounds__(256, 2) void conv_kernel(const ushort* __restrict__ wt2,
                                                      const ushort* __restrict__ xp2,
                                                      const float* __restrict__ q,
                                                      float* __restrict__ out) {
  __shared__ ushort As[3][4096];             // 24 KB
  __shared__ ushort Bs[2][6528];             // 2 x 13,056 B
  int blk = blockIdx.x;
  int b = blk & 63, tile = blk >> 6;
  int p0 = tile * 128, h0 = tile * 4;
  int t = threadIdx.x;
  int lane = t & 63, wv = t >> 6;
  int m0 = (wv & 1) * 64, n0 = (wv >> 1) * 64;
  int quad = lane >> 4, li = lane & 15;
  f32x4 acc[4][4] = {};
  const ushort* wtb = wt2 + (size_t)b * 147456;
  const ushort* xpb = xp2 + (size_t)b * 147968;   // 4*1156*32

  // stage A(tap,cq) -> As[buf] : 2 DMA instrs / wave
  auto stageA = [&](int tapi, int cqi, int buf) {
    const ushort* ag = wtb + (size_t)(tapi * 4 + cqi) * 4096;
    async16(ag + (size_t)t * 8,         &As[buf][0] + wv * 512);
    async16(ag + (size_t)(256 + t) * 8, &As[buf][0] + 2048 + wv * 512);
  };
  // stage B(cq) -> Bs[buf] : 816 16B-lines, 204/wave, 4 DMA instrs / wave
  auto stageB = [&](int cqi, int buf) {
    const ushort* bgp = xpb + (size_t)(cqi * 1156 + h0 * 34) * 32;
    int lb = wv * 204;
    async16(bgp + (size_t)(lb +       lane) * 8, &Bs[buf][0] + (lb      ) * 8);
    async16(bgp + (size_t)(lb +  64 + lane) * 8, &Bs[buf][0] + (lb +  64) * 8);
    async16(bgp + (size_t)(lb + 128 + lane) * 8, &Bs[buf][0] + (lb + 128) * 8);
    if (lane < 12)
      async16(bgp + (size_t)(lb + 192 + lane) * 8, &Bs[buf][0] + (lb + 192) * 8);
  };

  // prologue queue (per wave): B0(4), A0(2), A1(2)
  stageB(0, 0);
  stageA(0, 0, 0);   // A(s=0) = (tap0,cq0) -> As[0]
  stageA(1, 0, 1);   // A(s=1) = (tap1,cq0) -> As[1]

#define CSTEP(cq, tap, vm) do { \
    WAITBAR(vm); \
    if (9*(cq)+(tap)+2 <= 35) \
      stageA((9*(cq)+(tap)+2) % 9, (9*(cq)+(tap)+2) / 9, ((tap)+2) % 3); \
    if ((tap) == 6 && (cq) < 3) stageB((cq)+1, ((cq)+1) & 1); \
    __builtin_amdgcn_sched_barrier(0); \
    { const ushort* ar = &As[(tap) % 3][0]; \
      const ushort* br = &Bs[(cq) & 1][0]; \
      const int kh_ = (tap) / 3, kw_ = (tap) % 3; \
      bf16x8 af[4], bg[4]; \
      _Pragma("unroll") \
      for (int mi = 0; mi < 4; ++mi) \
        af[mi] = *(const bf16x8*)(ar + (m0 + mi*16 + li) * 32 + quad * 8); \
      _Pragma("unroll") \
      for (int ni = 0; ni < 4; ++ni) { \
        int pl = n0 + ni*16 + li; \
        int hh = pl >> 5, ww = pl & 31; \
        bg[ni] = *(const bf16x8*)(br + ((hh + kh_) * 34 + (ww + kw_)) * 32 + quad * 8); \
      } \
      _Pragma("unroll") \
      for (int mi = 0; mi < 4; ++mi) \
        _Pragma("unroll") \
        for (int ni = 0; ni < 4; ++ni) \
          acc[mi][ni] = __builtin_amdgcn_mfma_f32_16x16x32_bf16(af[mi], bg[ni], acc[mi][ni], 0, 0, 0); \
    } \
  } while (0)

  // vmcnt schedule (hand-derived, per-wave exact):
  //   steady state: wait A(s) with A(s+1),A(s+2-issue) newer -> vmcnt(2)
  //   taps 7,8 of cq<3: B(cq+1) also newer in queue        -> vmcnt(6)
  //   last step: full drain                                 -> vmcnt(0)
  CSTEP(0,0,2); CSTEP(0,1,2); CSTEP(0,2,2); CSTEP(0,3,2); CSTEP(0,4,2);
  CSTEP(0,5,2); CSTEP(0,6,2); CSTEP(0,7,6); CSTEP(0,8,6);
  CSTEP(1,0,2); CSTEP(1,1,2); CSTEP(1,2,2); CSTEP(1,3,2); CSTEP(1,4,2);
  CSTEP(1,5,2); CSTEP(1,6,2); CSTEP(1,7,6); CSTEP(1,8,6);
  CSTEP(2,0,2); CSTEP(2,1,2); CSTEP(2,2,2); CSTEP(2,3,2); CSTEP(2,4,2);
  CSTEP(2,5,2); CSTEP(2,6,2); CSTEP(2,7,6); CSTEP(2,8,6);
  CSTEP(3,0,2); CSTEP(3,1,2); CSTEP(3,2,2); CSTEP(3,3,2); CSTEP(3,4,2);
  CSTEP(3,5,2); CSTEP(3,6,2); CSTEP(3,7,2); CSTEP(3,8,0);
#undef CSTEP

  const float* qb = q + (size_t)b * QSTRIDE + WOFF;
  float* ob = out + (size_t)b * 128 * 1024 + p0;
#pragma unroll
  for (int mi = 0; mi < 4; ++mi) {
    int o0 = m0 + mi*16 + quad*4;
    float4 bias = *(const float4*)(qb + o0);
#pragma unroll
    for (int ni = 0; ni < 4; ++ni) {
      int pl = n0 + ni*16 + li;
      float* dp = ob + (size_t)o0 * 1024 + pl;
      f32x4 a = acc[mi][ni];
      dp[0]    = a.x + bias.x;
      dp[1024] = a.y + bias.y;
      dp[2048] = a.z + bias.z;
      dp[3072] = a.w + bias.w;
    }
  }
}

extern "C" void kernel_launch(void* const* d_in, const int* in_sizes, int n_in,
                              void* d_out, int out_size, void* d_ws, size_t ws_size,
                              hipStream_t stream) {
  const float* q   = (const float*)d_in[0];
  const float* lhs = (const float*)d_in[1];
  const float* rhs = (const float*)d_in[2];
  const float* pw  = (const float*)d_in[3];
  const float* pb  = (const float*)d_in[4];
  float* out = (float*)d_out;

  // workspace layout (37,879,808 B total)
  char* ws = (char*)d_ws;
  ushort* wt2  = (ushort*)(ws);               // 18,874,368 B : wt2[b][tap][cq][o][32]
  ushort* pwb2 = (ushort*)(ws + 18874368);    //     65,536 B : pwb2[cq][o][32]
  ushort* xp2  = (ushort*)(ws + 18939904);    // 18,939,904 B : xp2[b][cq][34][34][32]

  pack_w_kernel     <<<512, 256, 0, stream>>>(q, wt2);
  pack_pw_kernel    <<<16,  256, 0, stream>>>(pw, pwb2);
  zero_border_kernel<<<64,  256, 0, stream>>>(xp2);
  proj_kernel       <<<dim3(8, 64), 256, 0, stream>>>(pwb2, lhs, rhs, pb, xp2);
  conv_kernel       <<<512, 256, 0, stream>>>(wt2, xp2, q, out);
}